// Round 1
// baseline (746.561 us; speedup 1.0000x reference)
//
#include <hip/hip_runtime.h>

// ---------------------------------------------------------------------------
// Swin window-attention block, fused, bf16 MFMA (gfx950)
// ---------------------------------------------------------------------------
// sizes: x[32,64,64,384] f32, w_qkv[384,1152], b_qkv[1152], w_out[384,384],
//        b_out[384], bias_table[225,12]; out[32,64,64,384] f32.
// 2048 windows (blocks) x 64 tokens x 384 ch, 12 heads x 32.

using bf16x8 = __attribute__((ext_vector_type(8))) __bf16;
using f32x4  = __attribute__((ext_vector_type(4))) float;

#define TPB 512
#define SCALE_Q 0.17677669529663687f

// LDS byte offsets
constexpr int kOQ    = 0;        // q frags  [4][512] bf16 (4 KB)
constexpr int kOK    = 4096;     // k frags  [4][512]
constexpr int kOV    = 8192;     // v frags  [2 nt][2 kk][512]
constexpr int kOO    = 12288;    // O_h frags [4][512]
constexpr int kOP    = 16384;    // P frags  [4 mt][2 kk][512] (8 KB)
// [0,49152) doubles as x A-frag staging area during the prologue
constexpr int kOWQ   = 49152;    // wqkv frag slab for current head (72 KB)
constexpr int kOWO   = 122880;   // wout frag slab for current head (24 KB)
constexpr int kOBIAS = 147456;   // rel-bias table [29][12] f32
constexpr int kOBQKV = 148992;   // b_qkv (q part pre-scaled) [1152] f32
constexpr int kOBOUT = 153600;   // b_out [384] f32
constexpr int kOMTOK = 155136;   // per-token mask region id [64] int
constexpr int kSMEM  = 155392;

__device__ __forceinline__ f32x4 mfma16(bf16x8 a, bf16x8 b, f32x4 c) {
  return __builtin_amdgcn_mfma_f32_16x16x32_bf16(a, b, c, 0, 0, 0);
}

__device__ __forceinline__ void g2l16(const void* g, void* l) {
  __builtin_amdgcn_global_load_lds(
      (const __attribute__((address_space(1))) void*)g,
      (__attribute__((address_space(3))) void*)l, 16, 0, 0);
}

// ---------------- prep: w_qkv -> bf16 B-fragment layout --------------------
// frag f = h*72 + kk*6 + nt ; element (l, j) = B[k=kk*32+(l>>4)*8+j][n=nt*16+(l&15)]
// n (0..95) maps to qkv col part*384 + h*32 + e ; q part pre-scaled.
__global__ __launch_bounds__(64) void prep_wqkv(const float* __restrict__ wq,
                                                __bf16* __restrict__ dst) {
  int f = blockIdx.x, l = threadIdx.x;
  int h = f / 72, r = f % 72, kk = r / 6, nt = r % 6;
  int c96 = nt * 16 + (l & 15);
  int part = c96 >> 5, e = c96 & 31;
  int colg = part * 384 + h * 32 + e;
  int k0 = kk * 32 + (l >> 4) * 8;
  bf16x8 v;
#pragma unroll
  for (int j = 0; j < 8; ++j) {
    float xv = wq[(size_t)(k0 + j) * 1152 + colg];
    if (part == 0) xv *= SCALE_Q;
    v[j] = (__bf16)xv;
  }
  *reinterpret_cast<bf16x8*>(dst + (size_t)f * 512 + l * 8) = v;
}

// ---------------- prep: w_out -> bf16 B-fragment layout --------------------
// frag f = h*24 + nt ; element (l,j) = w_out[h*32+(l>>4)*8+j][nt*16+(l&15)]
__global__ __launch_bounds__(64) void prep_wout(const float* __restrict__ wo,
                                                __bf16* __restrict__ dst) {
  int f = blockIdx.x, l = threadIdx.x;
  int h = f / 24, nt = f % 24;
  int row0 = h * 32 + (l >> 4) * 8;
  int col = nt * 16 + (l & 15);
  bf16x8 v;
#pragma unroll
  for (int j = 0; j < 8; ++j) v[j] = (__bf16)wo[(size_t)(row0 + j) * 384 + col];
  *reinterpret_cast<bf16x8*>(dst + (size_t)f * 512 + l * 8) = v;
}

// --------------------------------- main ------------------------------------
__global__ void __launch_bounds__(TPB, 2) swin_main(
    const float* __restrict__ x, const float* __restrict__ b_qkv,
    const float* __restrict__ b_out, const float* __restrict__ btab,
    const __bf16* __restrict__ wsq, const __bf16* __restrict__ wso,
    float* __restrict__ out) {
  extern __shared__ char sm[];
  const int tid = threadIdx.x;
  const int l = tid & 63, wid = tid >> 6;
  const int l15 = l & 15, lq = l >> 4;
  const int mtw = wid & 3, ntg = wid >> 2;

  const int widx = blockIdx.x;
  const int bb = widx >> 6, wy = (widx >> 3) & 7, wx = widx & 7;

  // ---- prologue: issue wq(head0) staging (9 chunks of 1KB per wave) ----
#pragma unroll
  for (int r = 0; r < 9; ++r) {
    int q = wid * 9 + r;
    g2l16(wsq + q * 512 + l * 8, sm + kOWQ + (q << 10));
  }
  // ---- mask region per token / bias tables into LDS ----
  if (tid < 64) {
    int py = (wy << 3) + (tid >> 3), px = (wx << 3) + (tid & 7);
    int ry = (py < 56) ? 0 : ((py < 60) ? 1 : 2);
    int rx = (px < 56) ? 0 : ((px < 60) ? 1 : 2);
    reinterpret_cast<int*>(sm + kOMTOK)[tid] = ry * 3 + rx;
  }
  // bias_table rows 15..43 (idx = dy+dx+29), flattened: lds[i] = btab[i+180]
  if (tid < 348) reinterpret_cast<float*>(sm + kOBIAS)[tid] = btab[tid + 180];
  for (int i = tid; i < 1152; i += TPB) {
    float v = b_qkv[i];
    if (i < 384) v *= SCALE_Q;
    reinterpret_cast<float*>(sm + kOBQKV)[i] = v;
  }
  if (tid < 384) reinterpret_cast<float*>(sm + kOBOUT)[tid] = b_out[tid];

  // ---- stage shifted x window into A-fragment layout (bf16) ----
  {
    int r = tid >> 3, cg = tid & 7;
    int sy = ((wy << 3) + (r >> 3) + 4) & 63;
    int sx = ((wx << 3) + (r & 7) + 4) & 63;
    const float* xrow = x + (size_t)((((bb << 6) | sy) << 6) | sx) * 384;
    int mt = r >> 4, l2b = r & 15;
#pragma unroll
    for (int it = 0; it < 6; ++it) {
      int c0 = it * 64 + cg * 8;
      f32x4 a = *reinterpret_cast<const f32x4*>(xrow + c0);
      f32x4 b2 = *reinterpret_cast<const f32x4*>(xrow + c0 + 4);
      bf16x8 hv;
#pragma unroll
      for (int j = 0; j < 4; ++j) { hv[j] = (__bf16)a[j]; hv[4 + j] = (__bf16)b2[j]; }
      int kk = c0 >> 5;
      int lane2 = l2b | (((c0 >> 3) & 3) << 4);
      *reinterpret_cast<bf16x8*>(sm + ((mt * 12 + kk) << 10) + (lane2 << 4)) = hv;
    }
  }
  __syncthreads();  // drains x loads AND wq(0) staging

  // ---- each wave caches its M-tile A-frags (48 VGPR), then free the area ----
  bf16x8 axk[12];
#pragma unroll
  for (int kk = 0; kk < 12; ++kk)
    axk[kk] = *reinterpret_cast<const bf16x8*>(sm + ((mtw * 12 + kk) << 10) + (l << 4));
  asm volatile("s_waitcnt lgkmcnt(0)" ::: "memory");
  __builtin_amdgcn_s_barrier();

  f32x4 outAcc[12];
#pragma unroll
  for (int t = 0; t < 12; ++t) outAcc[t] = (f32x4){0.f, 0.f, 0.f, 0.f};

  for (int h = 0; h < 12; ++h) {
    // ---- (b) qkv GEMM for head h : out tile (mtw, ntg*3..+2) ----
    f32x4 acc[3];
#pragma unroll
    for (int tt = 0; tt < 3; ++tt) acc[tt] = (f32x4){0.f, 0.f, 0.f, 0.f};
#pragma unroll
    for (int kk = 0; kk < 12; ++kk) {
#pragma unroll
      for (int tt = 0; tt < 3; ++tt) {
        int nt = ntg * 3 + tt;
        bf16x8 b = *reinterpret_cast<const bf16x8*>(sm + kOWQ + ((kk * 6 + nt) << 10) + (l << 4));
        acc[tt] = mfma16(axk[kk], b, acc[tt]);
      }
    }
    // bias add + scatter q/k/v into fragment-layout LDS
    {
      const float* bq = reinterpret_cast<const float*>(sm + kOBQKV);
#pragma unroll
      for (int tt = 0; tt < 3; ++tt) {
        int nt = ntg * 3 + tt;
        int c96 = nt * 16 + l15;
        int part = c96 >> 5, e = c96 & 31;
        float bv = bq[part * 384 + h * 32 + e];
#pragma unroll
        for (int i = 0; i < 4; ++i) {
          float v = acc[tt][i] + bv;
          int row = mtw * 16 + lq * 4 + i;
          __bf16 hv = (__bf16)v;
          if (part == 0) {
            int lane2 = (row & 15) | (((e >> 3) & 3) << 4);
            *reinterpret_cast<__bf16*>(sm + kOQ + (mtw << 10) + (lane2 << 4) + ((e & 7) << 1)) = hv;
          } else if (part == 1) {
            int lane2 = (row & 15) | (((e >> 3) & 3) << 4);
            *reinterpret_cast<__bf16*>(sm + kOK + (mtw << 10) + (lane2 << 4) + ((e & 7) << 1)) = hv;
          } else {  // v, stored as PV B-frags (transposed)
            int lane2 = (e & 15) | (((row >> 3) & 3) << 4);
            *reinterpret_cast<__bf16*>(sm + kOV + ((((e >> 4) << 1) | (row >> 5)) << 10) +
                                       (lane2 << 4) + ((row & 7) << 1)) = hv;
          }
        }
      }
    }
    __syncthreads();  // (c) qkv visible; drains wout(h-1) loads -> wout LDS valid

    // ---- (d) prefetch next head's wqkv frags (fly across raw barriers) ----
    if (h < 11) {
#pragma unroll
      for (int r = 0; r < 9; ++r) {
        int q = wid * 9 + r;
        g2l16(wsq + (size_t)(h + 1) * 36864 + q * 512 + l * 8, sm + kOWQ + (q << 10));
      }
    }
    // ---- (e) out-projection of PREVIOUS head (overlaps with staging) ----
    if (h > 0) {
      bf16x8 aof = *reinterpret_cast<const bf16x8*>(sm + kOO + (mtw << 10) + (l << 4));
#pragma unroll
      for (int t = 0; t < 12; ++t) {
        bf16x8 b = *reinterpret_cast<const bf16x8*>(sm + kOWO + ((ntg * 12 + t) << 10) + (l << 4));
        outAcc[t] = mfma16(aof, b, outAcc[t]);
      }
    }
    __builtin_amdgcn_s_barrier();  // (f) wout region free; prefetches still in flight

    // ---- (g) prefetch this head's wout frags (needed next iteration) ----
#pragma unroll
    for (int r = 0; r < 3; ++r) {
      int q = wid * 3 + r;
      g2l16(wso + (size_t)h * 12288 + q * 512 + l * 8, sm + kOWO + (q << 10));
    }

    // ---- (h) S = q k^T + bias + mask, softmax, P -> frag LDS (waves 0-3) ----
    if (wid < 4) {
      const int smt = wid;
      bf16x8 aq = *reinterpret_cast<const bf16x8*>(sm + kOQ + (smt << 10) + (l << 4));
      f32x4 sac[4];
#pragma unroll
      for (int nt = 0; nt < 4; ++nt) {
        bf16x8 bk = *reinterpret_cast<const bf16x8*>(sm + kOK + (nt << 10) + (l << 4));
        f32x4 z = (f32x4){0.f, 0.f, 0.f, 0.f};
        sac[nt] = mfma16(aq, bk, z);
      }
      const int* mtk = reinterpret_cast<const int*>(sm + kOMTOK);
      const float* bft = reinterpret_cast<const float*>(sm + kOBIAS);
      int kt[4], mk[4], kyx[4];
#pragma unroll
      for (int nt = 0; nt < 4; ++nt) {
        kt[nt] = nt * 16 + l15;
        mk[nt] = mtk[kt[nt]];
        kyx[nt] = (kt[nt] >> 3) + (kt[nt] & 7);
      }
#pragma unroll
      for (int i = 0; i < 4; ++i) {
        int qtok = smt * 16 + lq * 4 + i;
        int mq = mtk[qtok];
        int qyx = (qtok >> 3) + (qtok & 7);
        float sv[4], mx = -3.0e38f;
#pragma unroll
        for (int nt = 0; nt < 4; ++nt) {
          float bias = bft[(qyx - kyx[nt] + 14) * 12 + h];
          float t = sac[nt][i] + bias + ((mq == mk[nt]) ? 0.f : -100.f);
          sv[nt] = t;
          mx = fmaxf(mx, t);
        }
#pragma unroll
        for (int off = 1; off <= 8; off <<= 1) mx = fmaxf(mx, __shfl_xor(mx, off));
        float se = 0.f;
#pragma unroll
        for (int nt = 0; nt < 4; ++nt) {
          sv[nt] = exp2f((sv[nt] - mx) * 1.4426950408889634f);
          se += sv[nt];
        }
#pragma unroll
        for (int off = 1; off <= 8; off <<= 1) se += __shfl_xor(se, off);
        float inv = 1.0f / se;
        int r15 = lq * 4 + i;
#pragma unroll
        for (int nt = 0; nt < 4; ++nt) {
          __bf16 p = (__bf16)(sv[nt] * inv);
          int ktt = kt[nt];
          int lane2 = r15 | (((ktt >> 3) & 3) << 4);
          *reinterpret_cast<__bf16*>(sm + kOP + (((smt << 1) | (ktt >> 5)) << 10) +
                                     (lane2 << 4) + ((ktt & 7) << 1)) = p;
        }
      }
    }
    asm volatile("s_waitcnt lgkmcnt(0)" ::: "memory");  // (i) P visible
    __builtin_amdgcn_s_barrier();

    // ---- (j) O_h = P @ V ; scatter O frags ----
    {
      f32x4 accO = (f32x4){0.f, 0.f, 0.f, 0.f};
#pragma unroll
      for (int k2 = 0; k2 < 2; ++k2) {
        bf16x8 ap = *reinterpret_cast<const bf16x8*>(sm + kOP + (((mtw << 1) | k2) << 10) + (l << 4));
        bf16x8 bv = *reinterpret_cast<const bf16x8*>(sm + kOV + (((ntg << 1) | k2) << 10) + (l << 4));
        accO = mfma16(ap, bv, accO);
      }
#pragma unroll
      for (int i = 0; i < 4; ++i) {
        int r15 = lq * 4 + i;
        int e = ntg * 16 + l15;
        int lane2 = r15 | (((e >> 3) & 3) << 4);
        *reinterpret_cast<__bf16*>(sm + kOO + (mtw << 10) + (lane2 << 4) + ((e & 7) << 1)) =
            (__bf16)accO[i];
      }
    }
    // (l) ensure wq(h+1) landed (3 wout loads may stay in flight) + O visible
    asm volatile("s_waitcnt vmcnt(3)" ::: "memory");
    asm volatile("s_waitcnt lgkmcnt(0)" ::: "memory");
    __builtin_amdgcn_s_barrier();
  }

  // ---- epilogue: out-projection of head 11, add b_out, store (reverse+roll) ----
  __syncthreads();  // drains wout(11) staging
  {
    bf16x8 aof = *reinterpret_cast<const bf16x8*>(sm + kOO + (mtw << 10) + (l << 4));
#pragma unroll
    for (int t = 0; t < 12; ++t) {
      bf16x8 b = *reinterpret_cast<const bf16x8*>(sm + kOWO + ((ntg * 12 + t) << 10) + (l << 4));
      outAcc[t] = mfma16(aof, b, outAcc[t]);
    }
    const float* bo = reinterpret_cast<const float*>(sm + kOBOUT);
#pragma unroll
    for (int t = 0; t < 12; ++t) {
      int col = (ntg * 12 + t) * 16 + l15;
      float bcv = bo[col];
#pragma unroll
      for (int i = 0; i < 4; ++i) {
        int row = mtw * 16 + lq * 4 + i;
        int sy = ((wy << 3) + (row >> 3) + 4) & 63;
        int sx = ((wx << 3) + (row & 7) + 4) & 63;
        out[(size_t)((((bb << 6) | sy) << 6) | sx) * 384 + col] = outAcc[t][i] + bcv;
      }
    }
  }
}

// ------------------------------ launch -------------------------------------
extern "C" void kernel_launch(void* const* d_in, const int* in_sizes, int n_in,
                              void* d_out, int out_size, void* d_ws, size_t ws_size,
                              hipStream_t stream) {
  const float* x = (const float*)d_in[0];
  const float* w_qkv = (const float*)d_in[1];
  const float* b_qkv = (const float*)d_in[2];
  const float* w_out = (const float*)d_in[3];
  const float* b_out = (const float*)d_in[4];
  const float* btab = (const float*)d_in[5];
  float* out = (float*)d_out;

  __bf16* wsq = (__bf16*)d_ws;          // 442368 bf16
  __bf16* wso = wsq + 442368;           // 147456 bf16

  hipFuncSetAttribute((const void*)swin_main,
                      hipFuncAttributeMaxDynamicSharedMemorySize, kSMEM);

  prep_wqkv<<<864, 64, 0, stream>>>(w_qkv, wsq);
  prep_wout<<<288, 64, 0, stream>>>(w_out, wso);
  swin_main<<<2048, TPB, kSMEM, stream>>>(x, b_qkv, b_out, btab, wsq, wso, out);
}